// Round 2
// baseline (1914.028 us; speedup 1.0000x reference)
//
#include <hip/hip_runtime.h>

constexpr int NN = 50000;
constexpr long long NE = 800000;
constexpr int C = 64;        // EIN == HID == OUT == 64
constexpr int IN_DIM = 128;
constexpr float NEG = 0.2f;

// ---- monotone float<->uint encoding for atomicMax on floats ----
__device__ __forceinline__ unsigned fenc(float f) {
    unsigned u = __float_as_uint(f);
    return (u & 0x80000000u) ? ~u : (u | 0x80000000u);
}
__device__ __forceinline__ float fdec(unsigned k) {
    unsigned u = (k & 0x80000000u) ? (k & 0x7FFFFFFFu) : ~k;
    return __uint_as_float(u);
}

// deg + loop_attr accumulation: one thread per (edge, channel)
__global__ void k_loopattr(const int* __restrict__ dst, const float* __restrict__ ea,
                           float* __restrict__ loop_attr, float* __restrict__ deg) {
    long long t = (long long)blockIdx.x * blockDim.x + threadIdx.x;
    if (t >= NE * C) return;
    int e = (int)(t >> 6), c = (int)(t & 63);
    int d = dst[e];
    atomicAdd(&loop_attr[(long long)d * C + c], ea[t]);
    if (c == 0) atomicAdd(&deg[d], 1.0f);
}

__global__ void k_loopdiv(float* __restrict__ loop_attr, const float* __restrict__ deg) {
    int t = blockIdx.x * blockDim.x + threadIdx.x;
    if (t >= NN * C) return;
    int n = t >> 6;
    loop_attr[t] /= fmaxf(deg[n], 1.0f);
}

// w = We @ a_e   (64 threads, one block)
__global__ void k_wvec(const float* __restrict__ We, const float* __restrict__ ae,
                       float* __restrict__ w) {
    int j = threadIdx.x;
    float s = 0.f;
    #pragma unroll
    for (int i = 0; i < C; ++i) s += We[j * C + i] * ae[i];
    w[j] = s;
}

// h = x @ W, plus a_src[n] = h.a_s, a_dst[n] = h.a_d  (one 64-lane wave per node)
template <int K>
__global__ void k_feat(const float* __restrict__ x, const float* __restrict__ W,
                       const float* __restrict__ as_, const float* __restrict__ ad_,
                       float* __restrict__ h, float* __restrict__ asrc,
                       float* __restrict__ adst) {
    __shared__ float xs[K];
    int n = blockIdx.x;
    int c = threadIdx.x;  // 0..63
    for (int k = c; k < K; k += C) xs[k] = x[(long long)n * K + k];
    __syncthreads();
    float hv = 0.f;
    #pragma unroll
    for (int k = 0; k < K; ++k) hv += xs[k] * W[k * C + c];
    h[(long long)n * C + c] = hv;
    float v1 = hv * as_[c], v2 = hv * ad_[c];
    for (int o = 32; o; o >>= 1) { v1 += __shfl_xor(v1, o); v2 += __shfl_xor(v2, o); }
    if (c == 0) { asrc[n] = v1; adst[n] = v2; }
}

// alpha per edge2 (E real edges + N self loops); wave per edge2
__global__ void k_alpha(const int* __restrict__ src, const int* __restrict__ dst,
                        const float* __restrict__ ea, const float* __restrict__ loop_attr,
                        const float* __restrict__ w, const float* __restrict__ asrc,
                        const float* __restrict__ adst, float* __restrict__ alpha,
                        unsigned* __restrict__ amax) {
    long long wid = ((long long)blockIdx.x * blockDim.x + threadIdx.x) >> 6;
    int lane = threadIdx.x & 63;
    if (wid >= NE + NN) return;
    int s, d;
    float av;
    if (wid < NE) {
        s = src[wid]; d = dst[wid];
        av = ea[wid * C + lane] * w[lane];
    } else {
        int n = (int)(wid - NE);
        s = n; d = n;
        av = loop_attr[(long long)n * C + lane] * w[lane];
    }
    for (int o = 32; o; o >>= 1) av += __shfl_xor(av, o);
    if (lane == 0) {
        float a = asrc[s] + adst[d] + av;
        a = a > 0.f ? a : NEG * a;
        alpha[wid] = a;
        atomicMax(&amax[d], fenc(a));
    }
}

// ex = exp(alpha - amax[dst]); denom[dst] += ex   (in-place into alpha buffer)
__global__ void k_ex(const int* __restrict__ dst, float* __restrict__ alpha,
                     const unsigned* __restrict__ amax, float* __restrict__ denom) {
    long long t = (long long)blockIdx.x * blockDim.x + threadIdx.x;
    if (t >= NE + NN) return;
    int d = (t < NE) ? dst[t] : (int)(t - NE);
    float ex = __expf(alpha[t] - fdec(amax[d]));
    alpha[t] = ex;
    atomicAdd(&denom[d], ex);
}

// acc[dst] += h[src] * (ex/denom[dst]) ; thread per (edge2, channel)
__global__ void k_agg(const int* __restrict__ src, const int* __restrict__ dst,
                      const float* __restrict__ ex, const float* __restrict__ denom,
                      const float* __restrict__ h, float* __restrict__ acc) {
    long long t = (long long)blockIdx.x * blockDim.x + threadIdx.x;
    if (t >= (NE + NN) * C) return;
    long long e2 = t >> 6;
    int c = (int)(t & 63);
    int s, d;
    if (e2 < NE) { s = src[e2]; d = dst[e2]; }
    else { s = d = (int)(e2 - NE); }
    float coef = ex[e2] / denom[d];
    atomicAdd(&acc[(long long)d * C + c], h[(long long)s * C + c] * coef);
}

// layer1 finalize: out = elu(acc + b)
__global__ void k_fin1(const float* __restrict__ acc, const float* __restrict__ b,
                       float* __restrict__ out) {
    int t = blockIdx.x * blockDim.x + threadIdx.x;
    if (t >= NN * C) return;
    float v = acc[t] + b[t & 63];
    out[t] = v > 0.f ? v : expm1f(v);
}

// layer2 finalize: out = acc + b
__global__ void k_fin2(const float* __restrict__ acc, const float* __restrict__ b,
                       float* __restrict__ out) {
    int t = blockIdx.x * blockDim.x + threadIdx.x;
    if (t >= NN * C) return;
    out[t] = acc[t] + b[t & 63];
}

// edge MLP: e = relu(ea@Wm1+bm1)@Wm2+bm2 ; 4 edges per 256-thread block
__global__ void k_mlp(const float* __restrict__ ea, const float* __restrict__ Wm1,
                      const float* __restrict__ bm1, const float* __restrict__ Wm2,
                      const float* __restrict__ bm2, float* __restrict__ eout) {
    __shared__ float sa[4][C];
    __shared__ float sh[4][C];
    int le = threadIdx.x >> 6, c = threadIdx.x & 63;
    long long e = (long long)blockIdx.x * 4 + le;   // NE % 4 == 0, no bounds check
    sa[le][c] = ea[e * C + c];
    __syncthreads();
    float hv = bm1[c];
    #pragma unroll
    for (int k = 0; k < C; ++k) hv += sa[le][k] * Wm1[k * C + c];
    hv = fmaxf(hv, 0.f);
    sh[le][c] = hv;
    __syncthreads();
    float ov = bm2[c];
    #pragma unroll
    for (int k = 0; k < C; ++k) ov += sh[le][k] * Wm2[k * C + c];
    eout[e * C + c] = ov;
}

__global__ void k_batch(const int* __restrict__ batch, float* __restrict__ out) {
    int t = blockIdx.x * blockDim.x + threadIdx.x;
    if (t >= NN) return;
    out[t] = (float)batch[t];
}

extern "C" void kernel_launch(void* const* d_in, const int* in_sizes, int n_in,
                              void* d_out, int out_size, void* d_ws, size_t ws_size,
                              hipStream_t stream) {
    const float* x     = (const float*)d_in[0];
    const int*   eidx  = (const int*)d_in[1];   // [2, E]
    const float* eattr = (const float*)d_in[2];
    const int*   batch = (const int*)d_in[3];
    const float* W1 = (const float*)d_in[4];
    const float* as1 = (const float*)d_in[5];
    const float* ad1 = (const float*)d_in[6];
    const float* We1 = (const float*)d_in[7];
    const float* ae1 = (const float*)d_in[8];
    const float* b1  = (const float*)d_in[9];
    const float* W2 = (const float*)d_in[10];
    const float* as2 = (const float*)d_in[11];
    const float* ad2 = (const float*)d_in[12];
    const float* We2 = (const float*)d_in[13];
    const float* ae2 = (const float*)d_in[14];
    const float* b2  = (const float*)d_in[15];
    const float* Wm1 = (const float*)d_in[16];
    const float* bm1 = (const float*)d_in[17];
    const float* Wm2 = (const float*)d_in[18];
    const float* bm2 = (const float*)d_in[19];

    const int* src = eidx;
    const int* dst = eidx + NE;

    float* out_h = (float*)d_out;                       // [NN, C]
    float* out_e = out_h + (long long)NN * C;           // [NE, C]
    float* out_b = out_e + NE * C;                      // [NN]

    // workspace layout (floats)
    float* wsf       = (float*)d_ws;
    float* loop_attr = wsf;                         // NN*C
    float* deg       = loop_attr + (long long)NN * C; // NN  (contiguous w/ loop_attr for one memset)
    float* h         = deg + NN;                    // NN*C
    float* asrc      = h + (long long)NN * C;       // NN
    float* adst      = asrc + NN;                   // NN
    float* alpha     = adst + NN;                   // NE+NN
    unsigned* amax   = (unsigned*)(alpha + NE + NN);// NN   (amax,denom,acc contiguous for one memset)
    float* denom     = (float*)(amax + NN);         // NN
    float* acc       = denom + NN;                  // NN*C
    float* out1      = acc + (long long)NN * C;     // NN*C
    float* wvec      = out1 + (long long)NN * C;    // C

    const long long NE2 = NE + NN;

    // ---- shared precompute: loop_attr (mean incoming edge_attr), edge MLP, batch ----
    hipMemsetAsync(loop_attr, 0, sizeof(float) * ((long long)NN * C + NN), stream);
    {
        long long tot = NE * C;
        k_loopattr<<<(tot + 255) / 256, 256, 0, stream>>>(dst, eattr, loop_attr, deg);
        k_loopdiv<<<(NN * C + 255) / 256, 256, 0, stream>>>(loop_attr, deg);
    }
    k_mlp<<<NE / 4, 256, 0, stream>>>(eattr, Wm1, bm1, Wm2, bm2, out_e);
    k_batch<<<(NN + 255) / 256, 256, 0, stream>>>(batch, out_b);

    // ---- GAT layer 1 ----
    k_wvec<<<1, 64, 0, stream>>>(We1, ae1, wvec);
    k_feat<IN_DIM><<<NN, 64, 0, stream>>>(x, W1, as1, ad1, h, asrc, adst);
    hipMemsetAsync(amax, 0, sizeof(float) * (NN + NN + (long long)NN * C), stream);
    k_alpha<<<(NE2 * 64 + 255) / 256, 256, 0, stream>>>(src, dst, eattr, loop_attr, wvec,
                                                        asrc, adst, alpha, amax);
    k_ex<<<(NE2 + 255) / 256, 256, 0, stream>>>(dst, alpha, amax, denom);
    k_agg<<<(NE2 * 64 + 255) / 256, 256, 0, stream>>>(src, dst, alpha, denom, h, acc);
    k_fin1<<<(NN * C + 255) / 256, 256, 0, stream>>>(acc, b1, out1);

    // ---- GAT layer 2 ----
    k_wvec<<<1, 64, 0, stream>>>(We2, ae2, wvec);
    k_feat<C><<<NN, 64, 0, stream>>>(out1, W2, as2, ad2, h, asrc, adst);
    hipMemsetAsync(amax, 0, sizeof(float) * (NN + NN + (long long)NN * C), stream);
    k_alpha<<<(NE2 * 64 + 255) / 256, 256, 0, stream>>>(src, dst, eattr, loop_attr, wvec,
                                                        asrc, adst, alpha, amax);
    k_ex<<<(NE2 + 255) / 256, 256, 0, stream>>>(dst, alpha, amax, denom);
    k_agg<<<(NE2 * 64 + 255) / 256, 256, 0, stream>>>(src, dst, alpha, denom, h, acc);
    k_fin2<<<(NN * C + 255) / 256, 256, 0, stream>>>(acc, b2, out_h);
}

// Round 3
// 674.425 us; speedup vs baseline: 2.8380x; 2.8380x over previous
//
#include <hip/hip_runtime.h>

constexpr int NN = 50000;
constexpr int NE = 800000;
constexpr int C = 64;        // EIN == HID == OUT == 64
constexpr int IN_DIM = 128;
constexpr float NEG = 0.2f;

// ============================================================
// wvec: wv[0..63] = We1 @ a_e1, wv[64..127] = We2 @ a_e2
// ============================================================
__global__ void k_wvec2(const float* __restrict__ We1, const float* __restrict__ vae1,
                        const float* __restrict__ We2, const float* __restrict__ vae2,
                        float* __restrict__ wv) {
    int t = threadIdx.x;           // 0..127
    int j = t & 63;
    const float* W = (t < 64) ? We1 : We2;
    const float* a = (t < 64) ? vae1 : vae2;
    float s = 0.f;
    #pragma unroll
    for (int i = 0; i < 64; ++i) s += W[j * 64 + i] * a[i];
    wv[t] = s;
}

// ============================================================
// Edge MLP (register-tiled GEMM) + fused a_edge dots.
// Tile: 128 edges x 64 ch. 256 threads; thread = 4 edges x 8 ch.
// LDS: xT[64][128] (transposed input, reused for hidden) + Ws[2][64][64].
// wv (128 floats) overlays Ws[1] during layer 1.
// ============================================================
__global__ __launch_bounds__(256, 2) void k_mlp2(
        const float* __restrict__ ea,
        const float* __restrict__ Wm1, const float* __restrict__ bm1,
        const float* __restrict__ Wm2, const float* __restrict__ bm2,
        const float* __restrict__ wv,
        float* __restrict__ eout, float* __restrict__ ae1, float* __restrict__ ae2) {
    __shared__ float xT[64 * 128];     // 32 KB  [k][e]
    __shared__ float Ws[2][64 * 64];   // 2x16 KB
    const int t = threadIdx.x;
    const long long E0 = (long long)blockIdx.x * 128;

    // stage W1; stage wv into Ws[1][0..127]
    {
        const float4* s1 = (const float4*)Wm1;
        float4* d1 = (float4*)Ws[0];
        #pragma unroll
        for (int i = 0; i < 4; ++i) d1[t + 256 * i] = s1[t + 256 * i];
        if (t < 128) Ws[1][t] = wv[t];
    }
    // stage input tile transposed: xT[k][e]
    {
        int e = t & 127, k0 = (t >> 7) * 32;
        const float4* srcp = (const float4*)(ea + (E0 + e) * 64 + k0);
        #pragma unroll
        for (int q = 0; q < 8; ++q) {
            float4 v = srcp[q];
            int k = k0 + q * 4;
            xT[(k + 0) * 128 + e] = v.x; xT[(k + 1) * 128 + e] = v.y;
            xT[(k + 2) * 128 + e] = v.z; xT[(k + 3) * 128 + e] = v.w;
        }
    }
    __syncthreads();

    const int eg = t >> 3, cg = t & 7;
    const int e0 = eg * 4, c0 = cg * 8;

    float acc[4][8], s1v[4], s2v[4];
    #pragma unroll
    for (int i = 0; i < 4; ++i) {
        s1v[i] = 0.f; s2v[i] = 0.f;
        #pragma unroll
        for (int j = 0; j < 8; ++j) acc[i][j] = 0.f;
    }

    #pragma unroll 4
    for (int k = 0; k < 64; ++k) {
        float4 a  = *(const float4*)&xT[k * 128 + e0];
        float4 w0 = *(const float4*)&Ws[0][k * 64 + c0];
        float4 w1 = *(const float4*)&Ws[0][k * 64 + c0 + 4];
        float wk1 = Ws[1][k], wk2 = Ws[1][64 + k];
        float av[4]  = {a.x, a.y, a.z, a.w};
        float wv8[8] = {w0.x, w0.y, w0.z, w0.w, w1.x, w1.y, w1.z, w1.w};
        #pragma unroll
        for (int i = 0; i < 4; ++i) {
            #pragma unroll
            for (int j = 0; j < 8; ++j) acc[i][j] += av[i] * wv8[j];
            s1v[i] += av[i] * wk1;
            s2v[i] += av[i] * wk2;
        }
    }
    if (cg == 0) {
        *(float4*)&ae1[E0 + e0] = make_float4(s1v[0], s1v[1], s1v[2], s1v[3]);
        *(float4*)&ae2[E0 + e0] = make_float4(s2v[0], s2v[1], s2v[2], s2v[3]);
    }
    // bias + relu
    float hv[4][8];
    #pragma unroll
    for (int j = 0; j < 8; ++j) {
        float b = bm1[c0 + j];
        #pragma unroll
        for (int i = 0; i < 4; ++i) hv[i][j] = fmaxf(acc[i][j] + b, 0.f);
    }
    __syncthreads();                       // everyone done reading xT & wv
    // write hidden transposed back into xT
    #pragma unroll
    for (int j = 0; j < 8; ++j)
        *(float4*)&xT[(c0 + j) * 128 + e0] =
            make_float4(hv[0][j], hv[1][j], hv[2][j], hv[3][j]);
    // stage W2 (overwrites wv overlay)
    {
        const float4* s2 = (const float4*)Wm2;
        float4* d2 = (float4*)Ws[1];
        #pragma unroll
        for (int i = 0; i < 4; ++i) d2[t + 256 * i] = s2[t + 256 * i];
    }
    __syncthreads();

    float acc2[4][8];
    #pragma unroll
    for (int i = 0; i < 4; ++i)
        #pragma unroll
        for (int j = 0; j < 8; ++j) acc2[i][j] = 0.f;

    #pragma unroll 4
    for (int k = 0; k < 64; ++k) {
        float4 a  = *(const float4*)&xT[k * 128 + e0];
        float4 w0 = *(const float4*)&Ws[1][k * 64 + c0];
        float4 w1 = *(const float4*)&Ws[1][k * 64 + c0 + 4];
        float av[4]  = {a.x, a.y, a.z, a.w};
        float wv8[8] = {w0.x, w0.y, w0.z, w0.w, w1.x, w1.y, w1.z, w1.w};
        #pragma unroll
        for (int i = 0; i < 4; ++i)
            #pragma unroll
            for (int j = 0; j < 8; ++j) acc2[i][j] += av[i] * wv8[j];
    }
    #pragma unroll
    for (int i = 0; i < 4; ++i) {
        float4 o0 = make_float4(acc2[i][0] + bm2[c0 + 0], acc2[i][1] + bm2[c0 + 1],
                                acc2[i][2] + bm2[c0 + 2], acc2[i][3] + bm2[c0 + 3]);
        float4 o1 = make_float4(acc2[i][4] + bm2[c0 + 4], acc2[i][5] + bm2[c0 + 5],
                                acc2[i][6] + bm2[c0 + 6], acc2[i][7] + bm2[c0 + 7]);
        *(float4*)&eout[(E0 + e0 + i) * 64 + c0]     = o0;
        *(float4*)&eout[(E0 + e0 + i) * 64 + c0 + 4] = o1;
    }
}

// ============================================================
// CSR build
// ============================================================
__global__ void k_hist(const int* __restrict__ dst, int* __restrict__ hist) {
    int t = blockIdx.x * blockDim.x + threadIdx.x;
    if (t >= NE) return;
    atomicAdd(&hist[dst[t]], 1);
}

// single-block exclusive scan of hist[NN] -> row_ptr, cursor
__global__ void k_scan(const int* __restrict__ hist, int* __restrict__ row_ptr,
                       int* __restrict__ cursor) {
    __shared__ int s[1024];
    const int PER = 49;                // 1024*49 = 50176 >= NN
    int t = threadIdx.x;
    int base = t * PER;
    int loc = 0;
    for (int i = 0; i < PER; ++i) {
        int idx = base + i;
        loc += (idx < NN) ? hist[idx] : 0;
    }
    s[t] = loc;
    __syncthreads();
    for (int off = 1; off < 1024; off <<= 1) {
        int x = (t >= off) ? s[t - off] : 0;
        __syncthreads();
        s[t] += x;
        __syncthreads();
    }
    int run = s[t] - loc;              // exclusive prefix for this thread's chunk
    for (int i = 0; i < PER; ++i) {
        int idx = base + i;
        if (idx < NN) {
            row_ptr[idx] = run; cursor[idx] = run;
            run += hist[idx];
        }
    }
    if (t == 0) row_ptr[NN] = NE;
}

// scatter edges into CSR records: {src_bits, ae1, ae2, 0}
__global__ void k_scatter(const int* __restrict__ src, const int* __restrict__ dst,
                          const float* __restrict__ ae1, const float* __restrict__ ae2,
                          int* __restrict__ cursor, float4* __restrict__ csr) {
    int t = blockIdx.x * blockDim.x + threadIdx.x;
    if (t >= NE) return;
    int d = dst[t];
    int pos = atomicAdd(&cursor[d], 1);
    csr[pos] = make_float4(__int_as_float(src[t]), ae1[t], ae2[t], 0.f);
}

// ============================================================
// h = x @ W, a_src = h.a_s, a_dst = h.a_d  (one wave per node)
// ============================================================
template <int K>
__global__ void k_feat(const float* __restrict__ x, const float* __restrict__ W,
                       const float* __restrict__ as_, const float* __restrict__ ad_,
                       float* __restrict__ h, float* __restrict__ asrc,
                       float* __restrict__ adst) {
    __shared__ float xs[K];
    int n = blockIdx.x;
    int c = threadIdx.x;  // 0..63
    for (int k = c; k < K; k += 64) xs[k] = x[(long long)n * K + k];
    __syncthreads();
    float hv = 0.f;
    #pragma unroll
    for (int k = 0; k < K; ++k) hv += xs[k] * W[k * 64 + c];
    h[(long long)n * 64 + c] = hv;
    float v1 = hv * as_[c], v2 = hv * ad_[c];
    for (int o = 32; o; o >>= 1) { v1 += __shfl_xor(v1, o); v2 += __shfl_xor(v2, o); }
    if (c == 0) { asrc[n] = v1; adst[n] = v2; }
}

// ============================================================
// Per-dst online-softmax GAT aggregation. One wave per node.
// ============================================================
template <bool IS_L1>
__global__ void k_gat(const int* __restrict__ row_ptr, const float4* __restrict__ csr,
                      const float* __restrict__ asrc, const float* __restrict__ adst,
                      const float* __restrict__ h, const float* __restrict__ bias,
                      float* __restrict__ out) {
    int n = blockIdx.x * 4 + (threadIdx.x >> 6);
    if (n >= NN) return;
    int lane = threadIdx.x & 63;
    int beg = row_ptr[n], end = row_ptr[n + 1];
    float adn = adst[n];
    float m = -INFINITY, l = 0.f, acc = 0.f, sum_ae = 0.f;

    float4 rcur = make_float4(0.f, 0.f, 0.f, 0.f);
    float hcur = 0.f, ascur = 0.f;
    if (beg < end) {
        rcur = csr[beg];
        int s = __float_as_int(rcur.x);
        hcur = h[s * 64 + lane];
        ascur = asrc[s];
    }
    for (int i = beg; i < end; ++i) {
        float4 rnext = rcur; float hnext = hcur, asnext = ascur;
        if (i + 1 < end) {                       // prefetch next edge
            rnext = csr[i + 1];
            int s2 = __float_as_int(rnext.x);
            hnext = h[s2 * 64 + lane];
            asnext = asrc[s2];
        }
        float ae = IS_L1 ? rcur.y : rcur.z;
        sum_ae += ae;
        float a = ascur + adn + ae;
        a = a > 0.f ? a : NEG * a;
        float mn = fmaxf(m, a);
        float sc = __expf(m - mn);
        float p  = __expf(a - mn);
        l = l * sc + p;
        acc = acc * sc + p * hcur;
        m = mn;
        rcur = rnext; hcur = hnext; ascur = asnext;
    }
    // self loop: ae_self = mean of ae over incoming edges (linearity of the dot)
    {
        float deg = (float)(end - beg);
        float ae = sum_ae / fmaxf(deg, 1.f);
        float a = asrc[n] + adn + ae;
        a = a > 0.f ? a : NEG * a;
        float hvn = h[n * 64 + lane];
        float mn = fmaxf(m, a);
        float sc = __expf(m - mn);
        float p  = __expf(a - mn);
        l = l * sc + p;
        acc = acc * sc + p * hvn;
    }
    float o = acc / l + bias[lane];
    if (IS_L1) o = o > 0.f ? o : expm1f(o);
    out[n * 64 + lane] = o;
}

__global__ void k_batch(const int* __restrict__ batch, float* __restrict__ out) {
    int t = blockIdx.x * blockDim.x + threadIdx.x;
    if (t >= NN) return;
    out[t] = (float)batch[t];
}

// ============================================================
extern "C" void kernel_launch(void* const* d_in, const int* in_sizes, int n_in,
                              void* d_out, int out_size, void* d_ws, size_t ws_size,
                              hipStream_t stream) {
    const float* x     = (const float*)d_in[0];
    const int*   eidx  = (const int*)d_in[1];   // [2, E] (int32 from harness)
    const float* eattr = (const float*)d_in[2];
    const int*   batch = (const int*)d_in[3];
    const float* W1 = (const float*)d_in[4];
    const float* as1 = (const float*)d_in[5];
    const float* ad1 = (const float*)d_in[6];
    const float* We1 = (const float*)d_in[7];
    const float* vae1 = (const float*)d_in[8];
    const float* b1  = (const float*)d_in[9];
    const float* W2 = (const float*)d_in[10];
    const float* as2 = (const float*)d_in[11];
    const float* ad2 = (const float*)d_in[12];
    const float* We2 = (const float*)d_in[13];
    const float* vae2 = (const float*)d_in[14];
    const float* b2  = (const float*)d_in[15];
    const float* Wm1 = (const float*)d_in[16];
    const float* bm1 = (const float*)d_in[17];
    const float* Wm2 = (const float*)d_in[18];
    const float* bm2 = (const float*)d_in[19];

    const int* src = eidx;
    const int* dst = eidx + NE;

    float* out_h = (float*)d_out;                     // [NN, 64]
    float* out_e = out_h + (long long)NN * C;         // [NE, 64]
    float* out_b = out_e + (long long)NE * C;         // [NN]

    // ---- workspace layout (csr first for 16B alignment) ----
    float4* csr   = (float4*)d_ws;                    // NE
    float* ae1    = (float*)(csr + NE);               // NE
    float* ae2    = ae1 + NE;                         // NE
    float* h      = ae2 + NE;                         // NN*64
    float* out1   = h + (long long)NN * C;            // NN*64
    float* asrc   = out1 + (long long)NN * C;         // NN
    float* adst   = asrc + NN;                        // NN
    float* wvec   = adst + NN;                        // 128
    int*   hist   = (int*)(wvec + 128);               // NN
    int*   row_ptr= hist + NN;                        // NN+1
    int*   cursor = row_ptr + NN + 1;                 // NN

    // ---- edge MLP + a_edge dots (single pass over edge_attr) ----
    k_wvec2<<<1, 128, 0, stream>>>(We1, vae1, We2, vae2, wvec);
    k_mlp2<<<NE / 128, 256, 0, stream>>>(eattr, Wm1, bm1, Wm2, bm2, wvec,
                                         out_e, ae1, ae2);

    // ---- CSR build ----
    hipMemsetAsync(hist, 0, sizeof(int) * NN, stream);
    k_hist<<<(NE + 255) / 256, 256, 0, stream>>>(dst, hist);
    k_scan<<<1, 1024, 0, stream>>>(hist, row_ptr, cursor);
    k_scatter<<<(NE + 255) / 256, 256, 0, stream>>>(src, dst, ae1, ae2, cursor, csr);

    // ---- GAT layer 1 ----
    k_feat<IN_DIM><<<NN, 64, 0, stream>>>(x, W1, as1, ad1, h, asrc, adst);
    k_gat<true><<<(NN + 3) / 4, 256, 0, stream>>>(row_ptr, csr, asrc, adst, h, b1, out1);

    // ---- GAT layer 2 ----
    k_feat<C><<<NN, 64, 0, stream>>>(out1, W2, as2, ad2, h, asrc, adst);
    k_gat<false><<<(NN + 3) / 4, 256, 0, stream>>>(row_ptr, csr, asrc, adst, h, b2, out_h);

    // ---- batch passthrough ----
    k_batch<<<(NN + 255) / 256, 256, 0, stream>>>(batch, out_b);
}

// Round 5
// 416.062 us; speedup vs baseline: 4.6003x; 1.6210x over previous
//
#include <hip/hip_runtime.h>

constexpr int NN = 50000;
constexpr int NE = 800000;
constexpr int C = 64;        // EIN == HID == OUT == 64
constexpr int IN_DIM = 128;
constexpr float NEG = 0.2f;

typedef __attribute__((ext_vector_type(8))) short short8;
typedef __attribute__((ext_vector_type(4))) float f32x4;

// ---- pure-integer bf16 RNE conversion (no HIP bf16 structs) ----
__device__ __forceinline__ unsigned short f2bf(float f) {
    unsigned u = __float_as_uint(f);
    unsigned r = 0x7FFFu + ((u >> 16) & 1u);
    return (unsigned short)((u + r) >> 16);
}
__device__ __forceinline__ unsigned pack_bf2(float a, float b) {
    return (unsigned)f2bf(a) | ((unsigned)f2bf(b) << 16);
}

// ============================================================
// All small vectors in one kernel (512 threads over 2 blocks):
// [0,64)   wv1 = We1 @ a_e1          [64,128)  wv2 = We2 @ a_e2
// [128,256) u1s = W1 @ a_s1          [256,384) u1d = W1 @ a_d1
// [384,448) u2s = W2 @ a_s2          [448,512) u2d = W2 @ a_d2
// ============================================================
__global__ void k_vecs(const float* __restrict__ We1, const float* __restrict__ ae1v,
                       const float* __restrict__ We2, const float* __restrict__ ae2v,
                       const float* __restrict__ W1, const float* __restrict__ as1,
                       const float* __restrict__ ad1,
                       const float* __restrict__ W2, const float* __restrict__ as2,
                       const float* __restrict__ ad2,
                       float* __restrict__ out) {
    int t = blockIdx.x * blockDim.x + threadIdx.x;   // 0..511
    const float* M; const float* v; int row;
    if      (t < 64)  { M = We1; v = ae1v; row = t; }
    else if (t < 128) { M = We2; v = ae2v; row = t - 64; }
    else if (t < 256) { M = W1;  v = as1;  row = t - 128; }
    else if (t < 384) { M = W1;  v = ad1;  row = t - 256; }
    else if (t < 448) { M = W2;  v = as2;  row = t - 384; }
    else              { M = W2;  v = ad2;  row = t - 448; }
    float s = 0.f;
    #pragma unroll
    for (int c = 0; c < 64; ++c) s += M[row * 64 + c] * v[c];
    out[t] = s;
}

// ============================================================
// Fused 2-layer edge MLP via MFMA bf16 + fp32 ae dots.
// 128 edges/block, 256 threads (4 waves), wave owns 32-edge stripe.
// ============================================================
__global__ __launch_bounds__(256) void k_mlp_mfma(
        const float* __restrict__ ea,
        const float* __restrict__ Wm1, const float* __restrict__ bm1,
        const float* __restrict__ Wm2, const float* __restrict__ bm2,
        const float* __restrict__ wv,   // [128] = wv1 | wv2
        float* __restrict__ eout, float* __restrict__ ae1, float* __restrict__ ae2) {
    constexpr int AP = 144;              // bytes per LDS row: (64+8) bf16
    __shared__ char Atile[128 * AP];     // 18 KB
    __shared__ char Bt1[64 * AP];        // 9 KB (W1^T bf16)
    __shared__ char Bt2[64 * AP];        // 9 KB (W2^T bf16)
    const int t = threadIdx.x;
    const long long E0 = (long long)blockIdx.x * 128;
    const int l = t & 63;

    // ---- stage A tile (coalesced float4) + fp32 ae dots ----
    {
        const int j = t & 15;            // k-quarter (4 floats)
        const int eb = t >> 4;           // 0..15
        float4 wk1 = *(const float4*)&wv[j * 4];
        float4 wk2 = *(const float4*)&wv[64 + j * 4];
        const float4* g = (const float4*)(ea + E0 * 64);
        float s1[8], s2[8];
        #pragma unroll
        for (int q = 0; q < 8; ++q) {
            float4 v = g[t + 256 * q];
            int e = eb + 16 * q;
            s1[q] = v.x * wk1.x + v.y * wk1.y + v.z * wk1.z + v.w * wk1.w;
            s2[q] = v.x * wk2.x + v.y * wk2.y + v.z * wk2.z + v.w * wk2.w;
            uint2 wr;
            wr.x = pack_bf2(v.x, v.y);
            wr.y = pack_bf2(v.z, v.w);
            *(uint2*)(Atile + e * AP + j * 8) = wr;
        }
        #pragma unroll
        for (int off = 1; off < 16; off <<= 1) {
            #pragma unroll
            for (int q = 0; q < 8; ++q) {
                s1[q] += __shfl_xor(s1[q], off);
                s2[q] += __shfl_xor(s2[q], off);
            }
        }
        float o1 = 0.f, o2 = 0.f;
        #pragma unroll
        for (int q = 0; q < 8; ++q) {    // static-index select (rule #20)
            if (j == q)     o1 = s1[q];
            if (j == q + 8) o2 = s2[q];
        }
        if (j < 8) ae1[E0 + eb + 16 * j] = o1;
        else       ae2[E0 + eb + 16 * (j - 8)] = o2;
    }
    // ---- stage Bt1/Bt2 = W^T bf16 ----
    {
        const int c = t & 63, kq = t >> 6;
        #pragma unroll
        for (int i = 0; i < 16; i += 2) {
            int k = kq * 16 + i;
            *(unsigned*)(Bt1 + c * AP + k * 2) = pack_bf2(Wm1[k * 64 + c], Wm1[(k + 1) * 64 + c]);
            *(unsigned*)(Bt2 + c * AP + k * 2) = pack_bf2(Wm2[k * 64 + c], Wm2[(k + 1) * 64 + c]);
        }
    }
    __syncthreads();

    const int m0 = (t >> 6) * 32;        // wave's 32-edge stripe
    const int lr = l & 15;
    const int lk = (l >> 4) * 8;

    // ---- layer 1 MFMA ----
    f32x4 acc[2][4] = {};
    #pragma unroll
    for (int ks = 0; ks < 2; ++ks) {
        int ko = ks * 32 + lk;
        short8 a0 = *(const short8*)(Atile + (m0 + lr) * AP + ko * 2);
        short8 a1 = *(const short8*)(Atile + (m0 + 16 + lr) * AP + ko * 2);
        #pragma unroll
        for (int nt = 0; nt < 4; ++nt) {
            short8 b = *(const short8*)(Bt1 + (nt * 16 + lr) * AP + ko * 2);
            acc[0][nt] = __builtin_amdgcn_mfma_f32_16x16x32_bf16(a0, b, acc[0][nt], 0, 0, 0);
            acc[1][nt] = __builtin_amdgcn_mfma_f32_16x16x32_bf16(a1, b, acc[1][nt], 0, 0, 0);
        }
    }
    // hidden: bias + relu -> back into the wave's own A stripe (no barrier needed)
    {
        float b1v[4];
        #pragma unroll
        for (int nt = 0; nt < 4; ++nt) b1v[nt] = bm1[nt * 16 + lr];
        #pragma unroll
        for (int mt = 0; mt < 2; ++mt)
        #pragma unroll
        for (int nt = 0; nt < 4; ++nt)
        #pragma unroll
        for (int r = 0; r < 4; ++r) {
            int row = m0 + mt * 16 + (l >> 4) * 4 + r;
            int col = nt * 16 + lr;
            float v = fmaxf(acc[mt][nt][r] + b1v[nt], 0.f);
            *(unsigned short*)(Atile + row * AP + col * 2) = f2bf(v);
        }
    }
    // ---- layer 2 MFMA ----
    f32x4 acc2[2][4] = {};
    #pragma unroll
    for (int ks = 0; ks < 2; ++ks) {
        int ko = ks * 32 + lk;
        short8 a0 = *(const short8*)(Atile + (m0 + lr) * AP + ko * 2);
        short8 a1 = *(const short8*)(Atile + (m0 + 16 + lr) * AP + ko * 2);
        #pragma unroll
        for (int nt = 0; nt < 4; ++nt) {
            short8 b = *(const short8*)(Bt2 + (nt * 16 + lr) * AP + ko * 2);
            acc2[0][nt] = __builtin_amdgcn_mfma_f32_16x16x32_bf16(a0, b, acc2[0][nt], 0, 0, 0);
            acc2[1][nt] = __builtin_amdgcn_mfma_f32_16x16x32_bf16(a1, b, acc2[1][nt], 0, 0, 0);
        }
    }
    {
        float b2v[4];
        #pragma unroll
        for (int nt = 0; nt < 4; ++nt) b2v[nt] = bm2[nt * 16 + lr];
        #pragma unroll
        for (int mt = 0; mt < 2; ++mt)
        #pragma unroll
        for (int nt = 0; nt < 4; ++nt)
        #pragma unroll
        for (int r = 0; r < 4; ++r) {
            int row = m0 + mt * 16 + (l >> 4) * 4 + r;
            eout[(E0 + row) * 64 + nt * 16 + lr] = acc2[mt][nt][r] + b2v[nt];
        }
    }
}

// ============================================================
// h = X @ W (MFMA bf16) + fp32 dots asrc = X@u_s, adst = X@u_d.
// 128 rows/block. uv = [u_s | u_d] (2K floats).
// ============================================================
template <int K>
__global__ __launch_bounds__(256) void k_feat_mfma(
        const float* __restrict__ x, const float* __restrict__ W,
        const float* __restrict__ uv,
        float* __restrict__ h, float* __restrict__ asrc, float* __restrict__ adst,
        int M) {
    constexpr int AP = K * 2 + 16;       // padded LDS row bytes
    constexpr int QW = K / 4;            // lanes per row-subgroup (16/32)
    constexpr int NQ = K / 8;            // float4s per thread (8/16)
    constexpr int EPQ = 256 / QW;        // row stride per q (16/8)
    __shared__ char Atile[128 * AP];
    __shared__ char Bt[64 * AP];
    const int t = threadIdx.x;
    const int M0 = blockIdx.x * 128;
    const int l = t & 63;

    // stage A + dots
    {
        const int j = t % QW;
        const int eb = t / QW;
        float4 wk1 = *(const float4*)&uv[j * 4];
        float4 wk2 = *(const float4*)&uv[K + j * 4];
        const float4* g = (const float4*)(x + (long long)M0 * K);
        float s1[NQ], s2[NQ];
        #pragma unroll
        for (int q = 0; q < NQ; ++q) {
            int e = eb + EPQ * q;
            float4 v = make_float4(0.f, 0.f, 0.f, 0.f);
            if (M0 + e < M) v = g[t + 256 * q];
            s1[q] = v.x * wk1.x + v.y * wk1.y + v.z * wk1.z + v.w * wk1.w;
            s2[q] = v.x * wk2.x + v.y * wk2.y + v.z * wk2.z + v.w * wk2.w;
            uint2 wr;
            wr.x = pack_bf2(v.x, v.y);
            wr.y = pack_bf2(v.z, v.w);
            *(uint2*)(Atile + e * AP + j * 8) = wr;
        }
        #pragma unroll
        for (int off = 1; off < QW; off <<= 1) {
            #pragma unroll
            for (int q = 0; q < NQ; ++q) {
                s1[q] += __shfl_xor(s1[q], off);
                s2[q] += __shfl_xor(s2[q], off);
            }
        }
        float o1 = 0.f, o2 = 0.f;
        #pragma unroll
        for (int q = 0; q < NQ; ++q) {
            if (j == q)      o1 = s1[q];
            if (j == q + NQ) o2 = s2[q];
        }
        if (j < NQ) { int e = eb + EPQ * j;        if (M0 + e < M) asrc[M0 + e] = o1; }
        else        { int e = eb + EPQ * (j - NQ); if (M0 + e < M) adst[M0 + e] = o2; }
    }
    // stage Bt = W^T bf16
    {
        const int c = t & 63, kq = t >> 6;
        #pragma unroll
        for (int i = 0; i < K / 4; i += 2) {
            int k = kq * (K / 4) + i;
            *(unsigned*)(Bt + c * AP + k * 2) = pack_bf2(W[k * 64 + c], W[(k + 1) * 64 + c]);
        }
    }
    __syncthreads();

    const int m0 = (t >> 6) * 32;
    const int lr = l & 15;
    const int lk = (l >> 4) * 8;

    f32x4 acc[2][4] = {};
    #pragma unroll
    for (int ks = 0; ks < K / 32; ++ks) {
        int ko = ks * 32 + lk;
        short8 a0 = *(const short8*)(Atile + (m0 + lr) * AP + ko * 2);
        short8 a1 = *(const short8*)(Atile + (m0 + 16 + lr) * AP + ko * 2);
        #pragma unroll
        for (int nt = 0; nt < 4; ++nt) {
            short8 b = *(const short8*)(Bt + (nt * 16 + lr) * AP + ko * 2);
            acc[0][nt] = __builtin_amdgcn_mfma_f32_16x16x32_bf16(a0, b, acc[0][nt], 0, 0, 0);
            acc[1][nt] = __builtin_amdgcn_mfma_f32_16x16x32_bf16(a1, b, acc[1][nt], 0, 0, 0);
        }
    }
    #pragma unroll
    for (int mt = 0; mt < 2; ++mt)
    #pragma unroll
    for (int nt = 0; nt < 4; ++nt)
    #pragma unroll
    for (int r = 0; r < 4; ++r) {
        int row = m0 + mt * 16 + (l >> 4) * 4 + r;
        if (M0 + row < M)
            h[(long long)(M0 + row) * 64 + nt * 16 + lr] = acc[mt][nt][r];
    }
}

// ============================================================
// CSR build
// ============================================================
__global__ void k_hist(const int* __restrict__ dst, int* __restrict__ hist) {
    int t = blockIdx.x * blockDim.x + threadIdx.x;
    if (t >= NE) return;
    atomicAdd(&hist[dst[t]], 1);
}

__global__ void k_scan(const int* __restrict__ hist, int* __restrict__ row_ptr,
                       int* __restrict__ cursor) {
    __shared__ int s[1024];
    const int PER = 49;
    int t = threadIdx.x;
    int base = t * PER;
    int loc = 0;
    for (int i = 0; i < PER; ++i) {
        int idx = base + i;
        loc += (idx < NN) ? hist[idx] : 0;
    }
    s[t] = loc;
    __syncthreads();
    for (int off = 1; off < 1024; off <<= 1) {
        int x = (t >= off) ? s[t - off] : 0;
        __syncthreads();
        s[t] += x;
        __syncthreads();
    }
    int run = s[t] - loc;
    for (int i = 0; i < PER; ++i) {
        int idx = base + i;
        if (idx < NN) {
            row_ptr[idx] = run; cursor[idx] = run;
            run += hist[idx];
        }
    }
    if (t == 0) row_ptr[NN] = NE;
}

__global__ void k_scatter(const int* __restrict__ src, const int* __restrict__ dst,
                          const float* __restrict__ ae1, const float* __restrict__ ae2,
                          int* __restrict__ cursor, float4* __restrict__ csr) {
    int t = blockIdx.x * blockDim.x + threadIdx.x;
    if (t >= NE) return;
    int d = dst[t];
    int pos = atomicAdd(&cursor[d], 1);
    csr[pos] = make_float4(__int_as_float(src[t]), ae1[t], ae2[t], 0.f);
}

// ============================================================
// GAT aggregation: wave per node, 4 subgroups of 16 lanes each
// walk interleaved edges with online softmax; shfl merge.
// ============================================================
template <bool IS_L1>
__global__ void k_gat(const int* __restrict__ row_ptr, const float4* __restrict__ csr,
                      const float* __restrict__ asrc, const float* __restrict__ adst,
                      const float* __restrict__ h, const float* __restrict__ bias,
                      float* __restrict__ out) {
    int n = blockIdx.x * 4 + (threadIdx.x >> 6);
    if (n >= NN) return;
    int lane = threadIdx.x & 63;
    int g = lane >> 4, s = lane & 15;
    int beg = row_ptr[n], end = row_ptr[n + 1];
    float adn = adst[n];
    float m = -1e30f, l = 0.f, sum_ae = 0.f;
    float4 acc = make_float4(0.f, 0.f, 0.f, 0.f);

    int i = beg + g;
    float4 rc = make_float4(0.f, 0.f, 0.f, 0.f);
    float4 hv = rc;
    float asv = 0.f;
    if (i < end) {
        rc = csr[i];
        int sr = __float_as_int(rc.x);
        hv = *(const float4*)&h[(long long)sr * 64 + s * 4];
        asv = asrc[sr];
    }
    for (; i < end; i += 4) {
        float4 rn = rc, hn = hv; float asn = asv;
        if (i + 4 < end) {
            rn = csr[i + 4];
            int sr2 = __float_as_int(rn.x);
            hn = *(const float4*)&h[(long long)sr2 * 64 + s * 4];
            asn = asrc[sr2];
        }
        float ae = IS_L1 ? rc.y : rc.z;
        sum_ae += ae;
        float a = asv + adn + ae;
        a = a > 0.f ? a : NEG * a;
        float mn = fmaxf(m, a);
        float sc = __expf(m - mn), p = __expf(a - mn);
        l = l * sc + p;
        acc.x = acc.x * sc + p * hv.x;
        acc.y = acc.y * sc + p * hv.y;
        acc.z = acc.z * sc + p * hv.z;
        acc.w = acc.w * sc + p * hv.w;
        m = mn;
        rc = rn; hv = hn; asv = asn;
    }
    // merge the 4 subgroups
    #pragma unroll
    for (int off = 16; off < 64; off <<= 1) {
        float mo = __shfl_xor(m, off);
        float lo = __shfl_xor(l, off);
        float ax = __shfl_xor(acc.x, off);
        float ay = __shfl_xor(acc.y, off);
        float az = __shfl_xor(acc.z, off);
        float aw = __shfl_xor(acc.w, off);
        float so = __shfl_xor(sum_ae, off);
        float mn = fmaxf(m, mo);
        float s1 = __expf(m - mn), s2 = __expf(mo - mn);
        l = l * s1 + lo * s2;
        acc.x = acc.x * s1 + ax * s2;
        acc.y = acc.y * s1 + ay * s2;
        acc.z = acc.z * s1 + az * s2;
        acc.w = acc.w * s1 + aw * s2;
        sum_ae += so;
        m = mn;
    }
    // self loop (ae_self = mean of incoming ae, by linearity)
    {
        float deg = (float)(end - beg);
        float ae = sum_ae / fmaxf(deg, 1.f);
        float a = asrc[n] + adn + ae;
        a = a > 0.f ? a : NEG * a;
        float4 hvn = *(const float4*)&h[(long long)n * 64 + s * 4];
        float mn = fmaxf(m, a);
        float sc = __expf(m - mn), p = __expf(a - mn);
        l = l * sc + p;
        acc.x = acc.x * sc + p * hvn.x;
        acc.y = acc.y * sc + p * hvn.y;
        acc.z = acc.z * sc + p * hvn.z;
        acc.w = acc.w * sc + p * hvn.w;
    }
    if (g == 0) {
        float4 o;
        o.x = acc.x / l + bias[s * 4 + 0];
        o.y = acc.y / l + bias[s * 4 + 1];
        o.z = acc.z / l + bias[s * 4 + 2];
        o.w = acc.w / l + bias[s * 4 + 3];
        if (IS_L1) {
            o.x = o.x > 0.f ? o.x : expm1f(o.x);
            o.y = o.y > 0.f ? o.y : expm1f(o.y);
            o.z = o.z > 0.f ? o.z : expm1f(o.z);
            o.w = o.w > 0.f ? o.w : expm1f(o.w);
        }
        *(float4*)&out[(long long)n * 64 + s * 4] = o;
    }
}

__global__ void k_batch(const int* __restrict__ batch, float* __restrict__ out) {
    int t = blockIdx.x * blockDim.x + threadIdx.x;
    if (t >= NN) return;
    out[t] = (float)batch[t];
}

// ============================================================
extern "C" void kernel_launch(void* const* d_in, const int* in_sizes, int n_in,
                              void* d_out, int out_size, void* d_ws, size_t ws_size,
                              hipStream_t stream) {
    const float* x     = (const float*)d_in[0];
    const int*   eidx  = (const int*)d_in[1];
    const float* eattr = (const float*)d_in[2];
    const int*   batch = (const int*)d_in[3];
    const float* W1 = (const float*)d_in[4];
    const float* as1 = (const float*)d_in[5];
    const float* ad1 = (const float*)d_in[6];
    const float* We1 = (const float*)d_in[7];
    const float* vae1 = (const float*)d_in[8];
    const float* b1  = (const float*)d_in[9];
    const float* W2 = (const float*)d_in[10];
    const float* as2 = (const float*)d_in[11];
    const float* ad2 = (const float*)d_in[12];
    const float* We2 = (const float*)d_in[13];
    const float* vae2 = (const float*)d_in[14];
    const float* b2  = (const float*)d_in[15];
    const float* Wm1 = (const float*)d_in[16];
    const float* bm1 = (const float*)d_in[17];
    const float* Wm2 = (const float*)d_in[18];
    const float* bm2 = (const float*)d_in[19];

    const int* src = eidx;
    const int* dst = eidx + NE;

    float* out_h = (float*)d_out;
    float* out_e = out_h + (long long)NN * C;
    float* out_b = out_e + (long long)NE * C;

    // workspace
    float4* csr   = (float4*)d_ws;                    // NE
    float* ae1    = (float*)(csr + NE);               // NE
    float* ae2    = ae1 + NE;                         // NE
    float* h      = ae2 + NE;                         // NN*64
    float* out1   = h + (long long)NN * C;            // NN*64
    float* asrc   = out1 + (long long)NN * C;         // NN
    float* adst   = asrc + NN;                        // NN
    float* vecs   = adst + NN;                        // 512
    int*   hist   = (int*)(vecs + 512);               // NN
    int*   row_ptr= hist + NN;                        // NN+1
    int*   cursor = row_ptr + NN + 1;                 // NN

    // small vectors
    k_vecs<<<2, 256, 0, stream>>>(We1, vae1, We2, vae2, W1, as1, ad1, W2, as2, ad2, vecs);

    // edge MLP + ae dots (single pass over edge_attr)
    k_mlp_mfma<<<NE / 128, 256, 0, stream>>>(eattr, Wm1, bm1, Wm2, bm2, vecs,
                                             out_e, ae1, ae2);

    // CSR build
    (void)hipMemsetAsync(hist, 0, sizeof(int) * NN, stream);
    k_hist<<<(NE + 255) / 256, 256, 0, stream>>>(dst, hist);
    k_scan<<<1, 1024, 0, stream>>>(hist, row_ptr, cursor);
    k_scatter<<<(NE + 255) / 256, 256, 0, stream>>>(src, dst, ae1, ae2, cursor, csr);

    // GAT layer 1
    k_feat_mfma<IN_DIM><<<(NN + 127) / 128, 256, 0, stream>>>(x, W1, vecs + 128,
                                                              h, asrc, adst, NN);
    k_gat<true><<<(NN + 3) / 4, 256, 0, stream>>>(row_ptr, csr, asrc, adst, h, b1, out1);

    // GAT layer 2
    k_feat_mfma<C><<<(NN + 127) / 128, 256, 0, stream>>>(out1, W2, vecs + 384,
                                                         h, asrc, adst, NN);
    k_gat<false><<<(NN + 3) / 4, 256, 0, stream>>>(row_ptr, csr, asrc, adst, h, b2, out_h);

    // batch passthrough
    k_batch<<<(NN + 255) / 256, 256, 0, stream>>>(batch, out_b);
}

// Round 6
// 304.889 us; speedup vs baseline: 6.2778x; 1.3646x over previous
//
#include <hip/hip_runtime.h>

constexpr int NN = 50000;
constexpr int NE = 800000;
constexpr int C = 64;        // EIN == HID == OUT == 64
constexpr int IN_DIM = 128;
constexpr float NEG = 0.2f;
constexpr int NB = (NN + 255) / 256;   // 196 scan blocks

typedef __attribute__((ext_vector_type(8))) short short8;
typedef __attribute__((ext_vector_type(4))) float f32x4;

// ---- pure-integer bf16 RNE conversion (no HIP bf16 structs) ----
__device__ __forceinline__ unsigned short f2bf(float f) {
    unsigned u = __float_as_uint(f);
    unsigned r = 0x7FFFu + ((u >> 16) & 1u);
    return (unsigned short)((u + r) >> 16);
}
__device__ __forceinline__ unsigned pack_bf2(float a, float b) {
    return (unsigned)f2bf(a) | ((unsigned)f2bf(b) << 16);
}

// ============================================================
// All small vectors in one kernel (512 threads over 2 blocks):
// [0,64)   wv1 = We1 @ a_e1          [64,128)  wv2 = We2 @ a_e2
// [128,256) u1s = W1 @ a_s1          [256,384) u1d = W1 @ a_d1
// [384,448) u2s = W2 @ a_s2          [448,512) u2d = W2 @ a_d2
// ============================================================
__global__ void k_vecs(const float* __restrict__ We1, const float* __restrict__ ae1v,
                       const float* __restrict__ We2, const float* __restrict__ ae2v,
                       const float* __restrict__ W1, const float* __restrict__ as1,
                       const float* __restrict__ ad1,
                       const float* __restrict__ W2, const float* __restrict__ as2,
                       const float* __restrict__ ad2,
                       float* __restrict__ out) {
    int t = blockIdx.x * blockDim.x + threadIdx.x;   // 0..511
    const float* M; const float* v; int row;
    if      (t < 64)  { M = We1; v = ae1v; row = t; }
    else if (t < 128) { M = We2; v = ae2v; row = t - 64; }
    else if (t < 256) { M = W1;  v = as1;  row = t - 128; }
    else if (t < 384) { M = W1;  v = ad1;  row = t - 256; }
    else if (t < 448) { M = W2;  v = as2;  row = t - 384; }
    else              { M = W2;  v = ad2;  row = t - 448; }
    float s = 0.f;
    #pragma unroll
    for (int c = 0; c < 64; ++c) s += M[row * 64 + c] * v[c];
    out[t] = s;
}

// ============================================================
// Fused 2-layer edge MLP via MFMA bf16 + fp32 ae dots.
// 128 edges/block, 256 threads (4 waves), wave owns 32-edge stripe.
// ============================================================
__global__ __launch_bounds__(256) void k_mlp_mfma(
        const float* __restrict__ ea,
        const float* __restrict__ Wm1, const float* __restrict__ bm1,
        const float* __restrict__ Wm2, const float* __restrict__ bm2,
        const float* __restrict__ wv,   // [128] = wv1 | wv2
        float* __restrict__ eout, float* __restrict__ ae1, float* __restrict__ ae2) {
    constexpr int AP = 144;              // bytes per LDS row: (64+8) bf16
    __shared__ char Atile[128 * AP];     // 18 KB
    __shared__ char Bt1[64 * AP];        // 9 KB (W1^T bf16)
    __shared__ char Bt2[64 * AP];        // 9 KB (W2^T bf16)
    const int t = threadIdx.x;
    const long long E0 = (long long)blockIdx.x * 128;
    const int l = t & 63;

    // ---- stage A tile (coalesced float4) + fp32 ae dots ----
    {
        const int j = t & 15;            // k-quarter (4 floats)
        const int eb = t >> 4;           // 0..15
        float4 wk1 = *(const float4*)&wv[j * 4];
        float4 wk2 = *(const float4*)&wv[64 + j * 4];
        const float4* g = (const float4*)(ea + E0 * 64);
        float s1[8], s2[8];
        #pragma unroll
        for (int q = 0; q < 8; ++q) {
            float4 v = g[t + 256 * q];
            int e = eb + 16 * q;
            s1[q] = v.x * wk1.x + v.y * wk1.y + v.z * wk1.z + v.w * wk1.w;
            s2[q] = v.x * wk2.x + v.y * wk2.y + v.z * wk2.z + v.w * wk2.w;
            uint2 wr;
            wr.x = pack_bf2(v.x, v.y);
            wr.y = pack_bf2(v.z, v.w);
            *(uint2*)(Atile + e * AP + j * 8) = wr;
        }
        #pragma unroll
        for (int off = 1; off < 16; off <<= 1) {
            #pragma unroll
            for (int q = 0; q < 8; ++q) {
                s1[q] += __shfl_xor(s1[q], off);
                s2[q] += __shfl_xor(s2[q], off);
            }
        }
        float o1 = 0.f, o2 = 0.f;
        #pragma unroll
        for (int q = 0; q < 8; ++q) {    // static-index select (rule #20)
            if (j == q)     o1 = s1[q];
            if (j == q + 8) o2 = s2[q];
        }
        if (j < 8) ae1[E0 + eb + 16 * j] = o1;
        else       ae2[E0 + eb + 16 * (j - 8)] = o2;
    }
    // ---- stage Bt1/Bt2 = W^T bf16 ----
    {
        const int c = t & 63, kq = t >> 6;
        #pragma unroll
        for (int i = 0; i < 16; i += 2) {
            int k = kq * 16 + i;
            *(unsigned*)(Bt1 + c * AP + k * 2) = pack_bf2(Wm1[k * 64 + c], Wm1[(k + 1) * 64 + c]);
            *(unsigned*)(Bt2 + c * AP + k * 2) = pack_bf2(Wm2[k * 64 + c], Wm2[(k + 1) * 64 + c]);
        }
    }
    __syncthreads();

    const int m0 = (t >> 6) * 32;        // wave's 32-edge stripe
    const int lr = l & 15;
    const int lk = (l >> 4) * 8;

    // ---- layer 1 MFMA ----
    f32x4 acc[2][4] = {};
    #pragma unroll
    for (int ks = 0; ks < 2; ++ks) {
        int ko = ks * 32 + lk;
        short8 a0 = *(const short8*)(Atile + (m0 + lr) * AP + ko * 2);
        short8 a1 = *(const short8*)(Atile + (m0 + 16 + lr) * AP + ko * 2);
        #pragma unroll
        for (int nt = 0; nt < 4; ++nt) {
            short8 b = *(const short8*)(Bt1 + (nt * 16 + lr) * AP + ko * 2);
            acc[0][nt] = __builtin_amdgcn_mfma_f32_16x16x32_bf16(a0, b, acc[0][nt], 0, 0, 0);
            acc[1][nt] = __builtin_amdgcn_mfma_f32_16x16x32_bf16(a1, b, acc[1][nt], 0, 0, 0);
        }
    }
    // hidden: bias + relu -> back into the wave's own A stripe (no barrier needed)
    {
        float b1v[4];
        #pragma unroll
        for (int nt = 0; nt < 4; ++nt) b1v[nt] = bm1[nt * 16 + lr];
        #pragma unroll
        for (int mt = 0; mt < 2; ++mt)
        #pragma unroll
        for (int nt = 0; nt < 4; ++nt)
        #pragma unroll
        for (int r = 0; r < 4; ++r) {
            int row = m0 + mt * 16 + (l >> 4) * 4 + r;
            int col = nt * 16 + lr;
            float v = fmaxf(acc[mt][nt][r] + b1v[nt], 0.f);
            *(unsigned short*)(Atile + row * AP + col * 2) = f2bf(v);
        }
    }
    // ---- layer 2 MFMA ----
    f32x4 acc2[2][4] = {};
    #pragma unroll
    for (int ks = 0; ks < 2; ++ks) {
        int ko = ks * 32 + lk;
        short8 a0 = *(const short8*)(Atile + (m0 + lr) * AP + ko * 2);
        short8 a1 = *(const short8*)(Atile + (m0 + 16 + lr) * AP + ko * 2);
        #pragma unroll
        for (int nt = 0; nt < 4; ++nt) {
            short8 b = *(const short8*)(Bt2 + (nt * 16 + lr) * AP + ko * 2);
            acc2[0][nt] = __builtin_amdgcn_mfma_f32_16x16x32_bf16(a0, b, acc2[0][nt], 0, 0, 0);
            acc2[1][nt] = __builtin_amdgcn_mfma_f32_16x16x32_bf16(a1, b, acc2[1][nt], 0, 0, 0);
        }
    }
    {
        float b2v[4];
        #pragma unroll
        for (int nt = 0; nt < 4; ++nt) b2v[nt] = bm2[nt * 16 + lr];
        #pragma unroll
        for (int mt = 0; mt < 2; ++mt)
        #pragma unroll
        for (int nt = 0; nt < 4; ++nt)
        #pragma unroll
        for (int r = 0; r < 4; ++r) {
            int row = m0 + mt * 16 + (l >> 4) * 4 + r;
            eout[(E0 + row) * 64 + nt * 16 + lr] = acc2[mt][nt][r] + b2v[nt];
        }
    }
}

// ============================================================
// h = X @ W (MFMA bf16) + fp32 dots asrc = X@u_s, adst = X@u_d.
// 128 rows/block. uv = [u_s | u_d] (2K floats).
// ============================================================
template <int K>
__global__ __launch_bounds__(256) void k_feat_mfma(
        const float* __restrict__ x, const float* __restrict__ W,
        const float* __restrict__ uv,
        float* __restrict__ h, float* __restrict__ asrc, float* __restrict__ adst,
        int M) {
    constexpr int AP = K * 2 + 16;       // padded LDS row bytes
    constexpr int QW = K / 4;            // lanes per row-subgroup (16/32)
    constexpr int NQ = K / 8;            // float4s per thread (8/16)
    constexpr int EPQ = 256 / QW;        // row stride per q (16/8)
    __shared__ char Atile[128 * AP];
    __shared__ char Bt[64 * AP];
    const int t = threadIdx.x;
    const int M0 = blockIdx.x * 128;
    const int l = t & 63;

    // stage A + dots
    {
        const int j = t % QW;
        const int eb = t / QW;
        float4 wk1 = *(const float4*)&uv[j * 4];
        float4 wk2 = *(const float4*)&uv[K + j * 4];
        const float4* g = (const float4*)(x + (long long)M0 * K);
        float s1[NQ], s2[NQ];
        #pragma unroll
        for (int q = 0; q < NQ; ++q) {
            int e = eb + EPQ * q;
            float4 v = make_float4(0.f, 0.f, 0.f, 0.f);
            if (M0 + e < M) v = g[t + 256 * q];
            s1[q] = v.x * wk1.x + v.y * wk1.y + v.z * wk1.z + v.w * wk1.w;
            s2[q] = v.x * wk2.x + v.y * wk2.y + v.z * wk2.z + v.w * wk2.w;
            uint2 wr;
            wr.x = pack_bf2(v.x, v.y);
            wr.y = pack_bf2(v.z, v.w);
            *(uint2*)(Atile + e * AP + j * 8) = wr;
        }
        #pragma unroll
        for (int off = 1; off < QW; off <<= 1) {
            #pragma unroll
            for (int q = 0; q < NQ; ++q) {
                s1[q] += __shfl_xor(s1[q], off);
                s2[q] += __shfl_xor(s2[q], off);
            }
        }
        float o1 = 0.f, o2 = 0.f;
        #pragma unroll
        for (int q = 0; q < NQ; ++q) {
            if (j == q)      o1 = s1[q];
            if (j == q + NQ) o2 = s2[q];
        }
        if (j < NQ) { int e = eb + EPQ * j;        if (M0 + e < M) asrc[M0 + e] = o1; }
        else        { int e = eb + EPQ * (j - NQ); if (M0 + e < M) adst[M0 + e] = o2; }
    }
    // stage Bt = W^T bf16
    {
        const int c = t & 63, kq = t >> 6;
        #pragma unroll
        for (int i = 0; i < K / 4; i += 2) {
            int k = kq * (K / 4) + i;
            *(unsigned*)(Bt + c * AP + k * 2) = pack_bf2(W[k * 64 + c], W[(k + 1) * 64 + c]);
        }
    }
    __syncthreads();

    const int m0 = (t >> 6) * 32;
    const int lr = l & 15;
    const int lk = (l >> 4) * 8;

    f32x4 acc[2][4] = {};
    #pragma unroll
    for (int ks = 0; ks < K / 32; ++ks) {
        int ko = ks * 32 + lk;
        short8 a0 = *(const short8*)(Atile + (m0 + lr) * AP + ko * 2);
        short8 a1 = *(const short8*)(Atile + (m0 + 16 + lr) * AP + ko * 2);
        #pragma unroll
        for (int nt = 0; nt < 4; ++nt) {
            short8 b = *(const short8*)(Bt + (nt * 16 + lr) * AP + ko * 2);
            acc[0][nt] = __builtin_amdgcn_mfma_f32_16x16x32_bf16(a0, b, acc[0][nt], 0, 0, 0);
            acc[1][nt] = __builtin_amdgcn_mfma_f32_16x16x32_bf16(a1, b, acc[1][nt], 0, 0, 0);
        }
    }
    #pragma unroll
    for (int mt = 0; mt < 2; ++mt)
    #pragma unroll
    for (int nt = 0; nt < 4; ++nt)
    #pragma unroll
    for (int r = 0; r < 4; ++r) {
        int row = m0 + mt * 16 + (l >> 4) * 4 + r;
        if (M0 + row < M)
            h[(long long)(M0 + row) * 64 + nt * 16 + lr] = acc[mt][nt][r];
    }
}

// ============================================================
// CSR build: hist -> 3-phase multi-block exclusive scan -> scatter
// ============================================================
__global__ void k_hist(const int* __restrict__ dst, int* __restrict__ hist) {
    int t = blockIdx.x * blockDim.x + threadIdx.x;
    if (t >= NE) return;
    atomicAdd(&hist[dst[t]], 1);
}

// phase 1: per-block exclusive scan (256 elems/block); row_ptr <- local prefix
__global__ void k_scan1(const int* __restrict__ hist, int* __restrict__ row_ptr,
                        int* __restrict__ bsum) {
    __shared__ int s[256];
    int t = threadIdx.x;
    int idx = blockIdx.x * 256 + t;
    int v = (idx < NN) ? hist[idx] : 0;
    s[t] = v;
    __syncthreads();
    #pragma unroll
    for (int off = 1; off < 256; off <<= 1) {
        int x = (t >= off) ? s[t - off] : 0;
        __syncthreads();
        s[t] += x;
        __syncthreads();
    }
    if (idx < NN) row_ptr[idx] = s[t] - v;      // local exclusive prefix
    if (t == 255) bsum[blockIdx.x] = s[255];    // block total
}

// phase 2: single-block exclusive scan of the NB block sums (in place)
__global__ void k_scan2(int* __restrict__ bsum) {
    __shared__ int s[256];
    int t = threadIdx.x;
    int v = (t < NB) ? bsum[t] : 0;
    s[t] = v;
    __syncthreads();
    #pragma unroll
    for (int off = 1; off < 256; off <<= 1) {
        int x = (t >= off) ? s[t - off] : 0;
        __syncthreads();
        s[t] += x;
        __syncthreads();
    }
    if (t < NB) bsum[t] = s[t] - v;             // exclusive block offset
}

// phase 3: add block offset; emit row_ptr + cursor
__global__ void k_scan3(const int* __restrict__ bsum, int* __restrict__ row_ptr,
                        int* __restrict__ cursor) {
    int idx = blockIdx.x * 256 + threadIdx.x;
    if (idx < NN) {
        int r = row_ptr[idx] + bsum[blockIdx.x];
        row_ptr[idx] = r;
        cursor[idx] = r;
    }
    if (idx == 0) row_ptr[NN] = NE;
}

__global__ void k_scatter(const int* __restrict__ src, const int* __restrict__ dst,
                          const float* __restrict__ ae1, const float* __restrict__ ae2,
                          int* __restrict__ cursor, float4* __restrict__ csr) {
    int t = blockIdx.x * blockDim.x + threadIdx.x;
    if (t >= NE) return;
    int d = dst[t];
    int pos = atomicAdd(&cursor[d], 1);
    csr[pos] = make_float4(__int_as_float(src[t]), ae1[t], ae2[t], 0.f);
}

// ============================================================
// GAT aggregation: wave per node, 4 subgroups of 16 lanes each
// walk interleaved edges with online softmax; shfl merge.
// ============================================================
template <bool IS_L1>
__global__ void k_gat(const int* __restrict__ row_ptr, const float4* __restrict__ csr,
                      const float* __restrict__ asrc, const float* __restrict__ adst,
                      const float* __restrict__ h, const float* __restrict__ bias,
                      float* __restrict__ out) {
    int n = blockIdx.x * 4 + (threadIdx.x >> 6);
    if (n >= NN) return;
    int lane = threadIdx.x & 63;
    int g = lane >> 4, s = lane & 15;
    int beg = row_ptr[n], end = row_ptr[n + 1];
    float adn = adst[n];
    float m = -1e30f, l = 0.f, sum_ae = 0.f;
    float4 acc = make_float4(0.f, 0.f, 0.f, 0.f);

    int i = beg + g;
    float4 rc = make_float4(0.f, 0.f, 0.f, 0.f);
    float4 hv = rc;
    float asv = 0.f;
    if (i < end) {
        rc = csr[i];
        int sr = __float_as_int(rc.x);
        hv = *(const float4*)&h[(long long)sr * 64 + s * 4];
        asv = asrc[sr];
    }
    for (; i < end; i += 4) {
        float4 rn = rc, hn = hv; float asn = asv;
        if (i + 4 < end) {
            rn = csr[i + 4];
            int sr2 = __float_as_int(rn.x);
            hn = *(const float4*)&h[(long long)sr2 * 64 + s * 4];
            asn = asrc[sr2];
        }
        float ae = IS_L1 ? rc.y : rc.z;
        sum_ae += ae;
        float a = asv + adn + ae;
        a = a > 0.f ? a : NEG * a;
        float mn = fmaxf(m, a);
        float sc = __expf(m - mn), p = __expf(a - mn);
        l = l * sc + p;
        acc.x = acc.x * sc + p * hv.x;
        acc.y = acc.y * sc + p * hv.y;
        acc.z = acc.z * sc + p * hv.z;
        acc.w = acc.w * sc + p * hv.w;
        m = mn;
        rc = rn; hv = hn; asv = asn;
    }
    // merge the 4 subgroups
    #pragma unroll
    for (int off = 16; off < 64; off <<= 1) {
        float mo = __shfl_xor(m, off);
        float lo = __shfl_xor(l, off);
        float ax = __shfl_xor(acc.x, off);
        float ay = __shfl_xor(acc.y, off);
        float az = __shfl_xor(acc.z, off);
        float aw = __shfl_xor(acc.w, off);
        float so = __shfl_xor(sum_ae, off);
        float mn = fmaxf(m, mo);
        float s1 = __expf(m - mn), s2 = __expf(mo - mn);
        l = l * s1 + lo * s2;
        acc.x = acc.x * s1 + ax * s2;
        acc.y = acc.y * s1 + ay * s2;
        acc.z = acc.z * s1 + az * s2;
        acc.w = acc.w * s1 + aw * s2;
        sum_ae += so;
        m = mn;
    }
    // self loop (ae_self = mean of incoming ae, by linearity)
    {
        float deg = (float)(end - beg);
        float ae = sum_ae / fmaxf(deg, 1.f);
        float a = asrc[n] + adn + ae;
        a = a > 0.f ? a : NEG * a;
        float4 hvn = *(const float4*)&h[(long long)n * 64 + s * 4];
        float mn = fmaxf(m, a);
        float sc = __expf(m - mn), p = __expf(a - mn);
        l = l * sc + p;
        acc.x = acc.x * sc + p * hvn.x;
        acc.y = acc.y * sc + p * hvn.y;
        acc.z = acc.z * sc + p * hvn.z;
        acc.w = acc.w * sc + p * hvn.w;
    }
    if (g == 0) {
        float4 o;
        o.x = acc.x / l + bias[s * 4 + 0];
        o.y = acc.y / l + bias[s * 4 + 1];
        o.z = acc.z / l + bias[s * 4 + 2];
        o.w = acc.w / l + bias[s * 4 + 3];
        if (IS_L1) {
            o.x = o.x > 0.f ? o.x : expm1f(o.x);
            o.y = o.y > 0.f ? o.y : expm1f(o.y);
            o.z = o.z > 0.f ? o.z : expm1f(o.z);
            o.w = o.w > 0.f ? o.w : expm1f(o.w);
        }
        *(float4*)&out[(long long)n * 64 + s * 4] = o;
    }
}

__global__ void k_batch(const int* __restrict__ batch, float* __restrict__ out) {
    int t = blockIdx.x * blockDim.x + threadIdx.x;
    if (t >= NN) return;
    out[t] = (float)batch[t];
}

// ============================================================
extern "C" void kernel_launch(void* const* d_in, const int* in_sizes, int n_in,
                              void* d_out, int out_size, void* d_ws, size_t ws_size,
                              hipStream_t stream) {
    const float* x     = (const float*)d_in[0];
    const int*   eidx  = (const int*)d_in[1];
    const float* eattr = (const float*)d_in[2];
    const int*   batch = (const int*)d_in[3];
    const float* W1 = (const float*)d_in[4];
    const float* as1 = (const float*)d_in[5];
    const float* ad1 = (const float*)d_in[6];
    const float* We1 = (const float*)d_in[7];
    const float* vae1 = (const float*)d_in[8];
    const float* b1  = (const float*)d_in[9];
    const float* W2 = (const float*)d_in[10];
    const float* as2 = (const float*)d_in[11];
    const float* ad2 = (const float*)d_in[12];
    const float* We2 = (const float*)d_in[13];
    const float* vae2 = (const float*)d_in[14];
    const float* b2  = (const float*)d_in[15];
    const float* Wm1 = (const float*)d_in[16];
    const float* bm1 = (const float*)d_in[17];
    const float* Wm2 = (const float*)d_in[18];
    const float* bm2 = (const float*)d_in[19];

    const int* src = eidx;
    const int* dst = eidx + NE;

    float* out_h = (float*)d_out;
    float* out_e = out_h + (long long)NN * C;
    float* out_b = out_e + (long long)NE * C;

    // workspace
    float4* csr   = (float4*)d_ws;                    // NE
    float* ae1    = (float*)(csr + NE);               // NE
    float* ae2    = ae1 + NE;                         // NE
    float* h      = ae2 + NE;                         // NN*64
    float* out1   = h + (long long)NN * C;            // NN*64
    float* asrc   = out1 + (long long)NN * C;         // NN
    float* adst   = asrc + NN;                        // NN
    float* vecs   = adst + NN;                        // 512
    int*   hist   = (int*)(vecs + 512);               // NN
    int*   row_ptr= hist + NN;                        // NN+1
    int*   cursor = row_ptr + NN + 1;                 // NN
    int*   bsum   = cursor + NN;                      // NB

    // small vectors
    k_vecs<<<2, 256, 0, stream>>>(We1, vae1, We2, vae2, W1, as1, ad1, W2, as2, ad2, vecs);

    // edge MLP + ae dots (single pass over edge_attr)
    k_mlp_mfma<<<NE / 128, 256, 0, stream>>>(eattr, Wm1, bm1, Wm2, bm2, vecs,
                                             out_e, ae1, ae2);

    // CSR build
    (void)hipMemsetAsync(hist, 0, sizeof(int) * NN, stream);
    k_hist<<<(NE + 255) / 256, 256, 0, stream>>>(dst, hist);
    k_scan1<<<NB, 256, 0, stream>>>(hist, row_ptr, bsum);
    k_scan2<<<1, 256, 0, stream>>>(bsum);
    k_scan3<<<NB, 256, 0, stream>>>(bsum, row_ptr, cursor);
    k_scatter<<<(NE + 255) / 256, 256, 0, stream>>>(src, dst, ae1, ae2, cursor, csr);

    // GAT layer 1
    k_feat_mfma<IN_DIM><<<(NN + 127) / 128, 256, 0, stream>>>(x, W1, vecs + 128,
                                                              h, asrc, adst, NN);
    k_gat<true><<<(NN + 3) / 4, 256, 0, stream>>>(row_ptr, csr, asrc, adst, h, b1, out1);

    // GAT layer 2
    k_feat_mfma<C><<<(NN + 127) / 128, 256, 0, stream>>>(out1, W2, vecs + 384,
                                                         h, asrc, adst, NN);
    k_gat<false><<<(NN + 3) / 4, 256, 0, stream>>>(row_ptr, csr, asrc, adst, h, b2, out_h);

    // batch passthrough
    k_batch<<<(NN + 255) / 256, 256, 0, stream>>>(batch, out_b);
}

// Round 7
// 277.584 us; speedup vs baseline: 6.8953x; 1.0984x over previous
//
#include <hip/hip_runtime.h>

constexpr int NN = 50000;
constexpr int NE = 800000;
constexpr int C = 64;        // EIN == HID == OUT == 64
constexpr int IN_DIM = 128;
constexpr float NEG = 0.2f;
constexpr int NB = (NN + 255) / 256;   // 196 scan blocks

typedef __attribute__((ext_vector_type(8))) short short8;
typedef __attribute__((ext_vector_type(4))) float f32x4;

// ---- pure-integer bf16 conversions (no HIP bf16 structs) ----
__device__ __forceinline__ unsigned short f2bf(float f) {
    unsigned u = __float_as_uint(f);
    unsigned r = 0x7FFFu + ((u >> 16) & 1u);
    return (unsigned short)((u + r) >> 16);
}
__device__ __forceinline__ unsigned pack_bf2(float a, float b) {
    return (unsigned)f2bf(a) | ((unsigned)f2bf(b) << 16);
}
__device__ __forceinline__ float bf2f(unsigned u) {
    return __uint_as_float(u << 16);
}

// ============================================================
// All small vectors in one kernel (512 threads over 2 blocks):
// [0,64)   wv1 = We1 @ a_e1          [64,128)  wv2 = We2 @ a_e2
// [128,256) u1s = W1 @ a_s1          [256,384) u1d = W1 @ a_d1
// [384,448) u2s = W2 @ a_s2          [448,512) u2d = W2 @ a_d2
// ============================================================
__global__ void k_vecs(const float* __restrict__ We1, const float* __restrict__ ae1v,
                       const float* __restrict__ We2, const float* __restrict__ ae2v,
                       const float* __restrict__ W1, const float* __restrict__ as1,
                       const float* __restrict__ ad1,
                       const float* __restrict__ W2, const float* __restrict__ as2,
                       const float* __restrict__ ad2,
                       float* __restrict__ out) {
    int t = blockIdx.x * blockDim.x + threadIdx.x;   // 0..511
    const float* M; const float* v; int row;
    if      (t < 64)  { M = We1; v = ae1v; row = t; }
    else if (t < 128) { M = We2; v = ae2v; row = t - 64; }
    else if (t < 256) { M = W1;  v = as1;  row = t - 128; }
    else if (t < 384) { M = W1;  v = ad1;  row = t - 256; }
    else if (t < 448) { M = W2;  v = as2;  row = t - 384; }
    else              { M = W2;  v = ad2;  row = t - 448; }
    float s = 0.f;
    #pragma unroll
    for (int c = 0; c < 64; ++c) s += M[row * 64 + c] * v[c];
    out[t] = s;
}

// ============================================================
// Fused 2-layer edge MLP via MFMA bf16 + fp32 ae dots + dst hist.
// 128 edges/block, 256 threads (4 waves), wave owns 32-edge stripe.
// ============================================================
__global__ __launch_bounds__(256) void k_mlp_mfma(
        const float* __restrict__ ea, const int* __restrict__ dst,
        const float* __restrict__ Wm1, const float* __restrict__ bm1,
        const float* __restrict__ Wm2, const float* __restrict__ bm2,
        const float* __restrict__ wv,   // [128] = wv1 | wv2
        float* __restrict__ eout, float* __restrict__ ae1, float* __restrict__ ae2,
        int* __restrict__ hist) {
    constexpr int AP = 144;              // bytes per LDS row: (64+8) bf16
    __shared__ char Atile[128 * AP];     // 18 KB
    __shared__ char Bt1[64 * AP];        // 9 KB (W1^T bf16)
    __shared__ char Bt2[64 * AP];        // 9 KB (W2^T bf16)
    const int t = threadIdx.x;
    const long long E0 = (long long)blockIdx.x * 128;
    const int l = t & 63;

    // fused degree histogram (one atomic per edge)
    if (t < 128) atomicAdd(&hist[dst[E0 + t]], 1);

    // ---- stage A tile (coalesced float4) + fp32 ae dots ----
    {
        const int j = t & 15;            // k-quarter (4 floats)
        const int eb = t >> 4;           // 0..15
        float4 wk1 = *(const float4*)&wv[j * 4];
        float4 wk2 = *(const float4*)&wv[64 + j * 4];
        const float4* g = (const float4*)(ea + E0 * 64);
        float s1[8], s2[8];
        #pragma unroll
        for (int q = 0; q < 8; ++q) {
            float4 v = g[t + 256 * q];
            int e = eb + 16 * q;
            s1[q] = v.x * wk1.x + v.y * wk1.y + v.z * wk1.z + v.w * wk1.w;
            s2[q] = v.x * wk2.x + v.y * wk2.y + v.z * wk2.z + v.w * wk2.w;
            uint2 wr;
            wr.x = pack_bf2(v.x, v.y);
            wr.y = pack_bf2(v.z, v.w);
            *(uint2*)(Atile + e * AP + j * 8) = wr;
        }
        #pragma unroll
        for (int off = 1; off < 16; off <<= 1) {
            #pragma unroll
            for (int q = 0; q < 8; ++q) {
                s1[q] += __shfl_xor(s1[q], off);
                s2[q] += __shfl_xor(s2[q], off);
            }
        }
        float o1 = 0.f, o2 = 0.f;
        #pragma unroll
        for (int q = 0; q < 8; ++q) {    // static-index select (rule #20)
            if (j == q)     o1 = s1[q];
            if (j == q + 8) o2 = s2[q];
        }
        if (j < 8) ae1[E0 + eb + 16 * j] = o1;
        else       ae2[E0 + eb + 16 * (j - 8)] = o2;
    }
    // ---- stage Bt1/Bt2 = W^T bf16 ----
    {
        const int c = t & 63, kq = t >> 6;
        #pragma unroll
        for (int i = 0; i < 16; i += 2) {
            int k = kq * 16 + i;
            *(unsigned*)(Bt1 + c * AP + k * 2) = pack_bf2(Wm1[k * 64 + c], Wm1[(k + 1) * 64 + c]);
            *(unsigned*)(Bt2 + c * AP + k * 2) = pack_bf2(Wm2[k * 64 + c], Wm2[(k + 1) * 64 + c]);
        }
    }
    __syncthreads();

    const int m0 = (t >> 6) * 32;        // wave's 32-edge stripe
    const int lr = l & 15;
    const int lk = (l >> 4) * 8;

    // ---- layer 1 MFMA ----
    f32x4 acc[2][4] = {};
    #pragma unroll
    for (int ks = 0; ks < 2; ++ks) {
        int ko = ks * 32 + lk;
        short8 a0 = *(const short8*)(Atile + (m0 + lr) * AP + ko * 2);
        short8 a1 = *(const short8*)(Atile + (m0 + 16 + lr) * AP + ko * 2);
        #pragma unroll
        for (int nt = 0; nt < 4; ++nt) {
            short8 b = *(const short8*)(Bt1 + (nt * 16 + lr) * AP + ko * 2);
            acc[0][nt] = __builtin_amdgcn_mfma_f32_16x16x32_bf16(a0, b, acc[0][nt], 0, 0, 0);
            acc[1][nt] = __builtin_amdgcn_mfma_f32_16x16x32_bf16(a1, b, acc[1][nt], 0, 0, 0);
        }
    }
    // hidden: bias + relu -> back into the wave's own A stripe (no barrier needed)
    {
        float b1v[4];
        #pragma unroll
        for (int nt = 0; nt < 4; ++nt) b1v[nt] = bm1[nt * 16 + lr];
        #pragma unroll
        for (int mt = 0; mt < 2; ++mt)
        #pragma unroll
        for (int nt = 0; nt < 4; ++nt)
        #pragma unroll
        for (int r = 0; r < 4; ++r) {
            int row = m0 + mt * 16 + (l >> 4) * 4 + r;
            int col = nt * 16 + lr;
            float v = fmaxf(acc[mt][nt][r] + b1v[nt], 0.f);
            *(unsigned short*)(Atile + row * AP + col * 2) = f2bf(v);
        }
    }
    // ---- layer 2 MFMA ----
    f32x4 acc2[2][4] = {};
    #pragma unroll
    for (int ks = 0; ks < 2; ++ks) {
        int ko = ks * 32 + lk;
        short8 a0 = *(const short8*)(Atile + (m0 + lr) * AP + ko * 2);
        short8 a1 = *(const short8*)(Atile + (m0 + 16 + lr) * AP + ko * 2);
        #pragma unroll
        for (int nt = 0; nt < 4; ++nt) {
            short8 b = *(const short8*)(Bt2 + (nt * 16 + lr) * AP + ko * 2);
            acc2[0][nt] = __builtin_amdgcn_mfma_f32_16x16x32_bf16(a0, b, acc2[0][nt], 0, 0, 0);
            acc2[1][nt] = __builtin_amdgcn_mfma_f32_16x16x32_bf16(a1, b, acc2[1][nt], 0, 0, 0);
        }
    }
    {
        float b2v[4];
        #pragma unroll
        for (int nt = 0; nt < 4; ++nt) b2v[nt] = bm2[nt * 16 + lr];
        #pragma unroll
        for (int mt = 0; mt < 2; ++mt)
        #pragma unroll
        for (int nt = 0; nt < 4; ++nt)
        #pragma unroll
        for (int r = 0; r < 4; ++r) {
            int row = m0 + mt * 16 + (l >> 4) * 4 + r;
            eout[(E0 + row) * 64 + nt * 16 + lr] = acc2[mt][nt][r] + b2v[nt];
        }
    }
}

// ============================================================
// h = X @ W (MFMA bf16, stored bf16) + fp32 dots asrc, adst.
// 128 rows/block. uv = [u_s | u_d] (2K floats).
// ============================================================
template <int K>
__global__ __launch_bounds__(256) void k_feat_mfma(
        const float* __restrict__ x, const float* __restrict__ W,
        const float* __restrict__ uv,
        unsigned short* __restrict__ h, float* __restrict__ asrc,
        float* __restrict__ adst, int M) {
    constexpr int AP = K * 2 + 16;       // padded LDS row bytes
    constexpr int QW = K / 4;            // lanes per row-subgroup (16/32)
    constexpr int NQ = K / 8;            // float4s per thread (8/16)
    constexpr int EPQ = 256 / QW;        // row stride per q (16/8)
    __shared__ char Atile[128 * AP];
    __shared__ char Bt[64 * AP];
    const int t = threadIdx.x;
    const int M0 = blockIdx.x * 128;
    const int l = t & 63;

    // stage A + dots
    {
        const int j = t % QW;
        const int eb = t / QW;
        float4 wk1 = *(const float4*)&uv[j * 4];
        float4 wk2 = *(const float4*)&uv[K + j * 4];
        const float4* g = (const float4*)(x + (long long)M0 * K);
        float s1[NQ], s2[NQ];
        #pragma unroll
        for (int q = 0; q < NQ; ++q) {
            int e = eb + EPQ * q;
            float4 v = make_float4(0.f, 0.f, 0.f, 0.f);
            if (M0 + e < M) v = g[t + 256 * q];
            s1[q] = v.x * wk1.x + v.y * wk1.y + v.z * wk1.z + v.w * wk1.w;
            s2[q] = v.x * wk2.x + v.y * wk2.y + v.z * wk2.z + v.w * wk2.w;
            uint2 wr;
            wr.x = pack_bf2(v.x, v.y);
            wr.y = pack_bf2(v.z, v.w);
            *(uint2*)(Atile + e * AP + j * 8) = wr;
        }
        #pragma unroll
        for (int off = 1; off < QW; off <<= 1) {
            #pragma unroll
            for (int q = 0; q < NQ; ++q) {
                s1[q] += __shfl_xor(s1[q], off);
                s2[q] += __shfl_xor(s2[q], off);
            }
        }
        float o1 = 0.f, o2 = 0.f;
        #pragma unroll
        for (int q = 0; q < NQ; ++q) {
            if (j == q)      o1 = s1[q];
            if (j == q + NQ) o2 = s2[q];
        }
        if (j < NQ) { int e = eb + EPQ * j;        if (M0 + e < M) asrc[M0 + e] = o1; }
        else        { int e = eb + EPQ * (j - NQ); if (M0 + e < M) adst[M0 + e] = o2; }
    }
    // stage Bt = W^T bf16
    {
        const int c = t & 63, kq = t >> 6;
        #pragma unroll
        for (int i = 0; i < K / 4; i += 2) {
            int k = kq * (K / 4) + i;
            *(unsigned*)(Bt + c * AP + k * 2) = pack_bf2(W[k * 64 + c], W[(k + 1) * 64 + c]);
        }
    }
    __syncthreads();

    const int m0 = (t >> 6) * 32;
    const int lr = l & 15;
    const int lk = (l >> 4) * 8;

    f32x4 acc[2][4] = {};
    #pragma unroll
    for (int ks = 0; ks < K / 32; ++ks) {
        int ko = ks * 32 + lk;
        short8 a0 = *(const short8*)(Atile + (m0 + lr) * AP + ko * 2);
        short8 a1 = *(const short8*)(Atile + (m0 + 16 + lr) * AP + ko * 2);
        #pragma unroll
        for (int nt = 0; nt < 4; ++nt) {
            short8 b = *(const short8*)(Bt + (nt * 16 + lr) * AP + ko * 2);
            acc[0][nt] = __builtin_amdgcn_mfma_f32_16x16x32_bf16(a0, b, acc[0][nt], 0, 0, 0);
            acc[1][nt] = __builtin_amdgcn_mfma_f32_16x16x32_bf16(a1, b, acc[1][nt], 0, 0, 0);
        }
    }
    #pragma unroll
    for (int mt = 0; mt < 2; ++mt)
    #pragma unroll
    for (int nt = 0; nt < 4; ++nt)
    #pragma unroll
    for (int r = 0; r < 4; ++r) {
        int row = m0 + mt * 16 + (l >> 4) * 4 + r;
        if (M0 + row < M)
            h[(long long)(M0 + row) * 64 + nt * 16 + lr] = f2bf(acc[mt][nt][r]);
    }
}

// ============================================================
// CSR build: 3-phase multi-block exclusive scan -> scatter
// ============================================================
__global__ void k_scan1(const int* __restrict__ hist, int* __restrict__ row_ptr,
                        int* __restrict__ bsum) {
    __shared__ int s[256];
    int t = threadIdx.x;
    int idx = blockIdx.x * 256 + t;
    int v = (idx < NN) ? hist[idx] : 0;
    s[t] = v;
    __syncthreads();
    #pragma unroll
    for (int off = 1; off < 256; off <<= 1) {
        int x = (t >= off) ? s[t - off] : 0;
        __syncthreads();
        s[t] += x;
        __syncthreads();
    }
    if (idx < NN) row_ptr[idx] = s[t] - v;      // local exclusive prefix
    if (t == 255) bsum[blockIdx.x] = s[255];    // block total
}

__global__ void k_scan2(int* __restrict__ bsum) {
    __shared__ int s[256];
    int t = threadIdx.x;
    int v = (t < NB) ? bsum[t] : 0;
    s[t] = v;
    __syncthreads();
    #pragma unroll
    for (int off = 1; off < 256; off <<= 1) {
        int x = (t >= off) ? s[t - off] : 0;
        __syncthreads();
        s[t] += x;
        __syncthreads();
    }
    if (t < NB) bsum[t] = s[t] - v;             // exclusive block offset
}

__global__ void k_scan3(const int* __restrict__ bsum, int* __restrict__ row_ptr,
                        int* __restrict__ cursor) {
    int idx = blockIdx.x * 256 + threadIdx.x;
    if (idx < NN) {
        int r = row_ptr[idx] + bsum[blockIdx.x];
        row_ptr[idx] = r;
        cursor[idx] = r;
    }
    if (idx == 0) row_ptr[NN] = NE;
}

// scatter 8-byte records: {src, ae1|ae2 packed bf16}
__global__ void k_scatter(const int* __restrict__ src, const int* __restrict__ dst,
                          const float* __restrict__ ae1, const float* __restrict__ ae2,
                          int* __restrict__ cursor, uint2* __restrict__ csr) {
    int t = blockIdx.x * blockDim.x + threadIdx.x;
    if (t >= NE) return;
    int d = dst[t];
    int pos = atomicAdd(&cursor[d], 1);
    csr[pos] = make_uint2((unsigned)src[t], pack_bf2(ae1[t], ae2[t]));
}

// ============================================================
// GAT aggregation: wave per node, 4 subgroups of 16 lanes each
// walk interleaved edges with online softmax; shfl merge.
// h is bf16-packed; csr records are 8 B.
// ============================================================
template <bool IS_L1>
__global__ void k_gat(const int* __restrict__ row_ptr, const uint2* __restrict__ csr,
                      const float* __restrict__ asrc, const float* __restrict__ adst,
                      const unsigned short* __restrict__ h, const float* __restrict__ bias,
                      float* __restrict__ out) {
    int n = blockIdx.x * 4 + (threadIdx.x >> 6);
    if (n >= NN) return;
    int lane = threadIdx.x & 63;
    int g = lane >> 4, s = lane & 15;
    int beg = row_ptr[n], end = row_ptr[n + 1];
    float adn = adst[n];
    float m = -1e30f, l = 0.f, sum_ae = 0.f;
    float4 acc = make_float4(0.f, 0.f, 0.f, 0.f);

    int i = beg + g;
    uint2 rc = make_uint2(0u, 0u);
    ushort4 hu = make_ushort4(0, 0, 0, 0);
    float asv = 0.f;
    if (i < end) {
        rc = csr[i];
        hu = *(const ushort4*)&h[(long long)rc.x * 64 + s * 4];
        asv = asrc[rc.x];
    }
    for (; i < end; i += 4) {
        uint2 rn = rc; ushort4 hn = hu; float asn = asv;
        if (i + 4 < end) {
            rn = csr[i + 4];
            hn = *(const ushort4*)&h[(long long)rn.x * 64 + s * 4];
            asn = asrc[rn.x];
        }
        float ae = IS_L1 ? bf2f(rc.y & 0xFFFFu) : bf2f(rc.y >> 16);
        sum_ae += ae;
        float a = asv + adn + ae;
        a = a > 0.f ? a : NEG * a;
        float mn = fmaxf(m, a);
        float sc = __expf(m - mn), p = __expf(a - mn);
        l = l * sc + p;
        acc.x = acc.x * sc + p * bf2f(hu.x);
        acc.y = acc.y * sc + p * bf2f(hu.y);
        acc.z = acc.z * sc + p * bf2f(hu.z);
        acc.w = acc.w * sc + p * bf2f(hu.w);
        m = mn;
        rc = rn; hu = hn; asv = asn;
    }
    // merge the 4 subgroups
    #pragma unroll
    for (int off = 16; off < 64; off <<= 1) {
        float mo = __shfl_xor(m, off);
        float lo = __shfl_xor(l, off);
        float ax = __shfl_xor(acc.x, off);
        float ay = __shfl_xor(acc.y, off);
        float az = __shfl_xor(acc.z, off);
        float aw = __shfl_xor(acc.w, off);
        float so = __shfl_xor(sum_ae, off);
        float mn = fmaxf(m, mo);
        float s1 = __expf(m - mn), s2 = __expf(mo - mn);
        l = l * s1 + lo * s2;
        acc.x = acc.x * s1 + ax * s2;
        acc.y = acc.y * s1 + ay * s2;
        acc.z = acc.z * s1 + az * s2;
        acc.w = acc.w * s1 + aw * s2;
        sum_ae += so;
        m = mn;
    }
    // self loop (ae_self = mean of incoming ae, by linearity)
    {
        float deg = (float)(end - beg);
        float ae = sum_ae / fmaxf(deg, 1.f);
        float a = asrc[n] + adn + ae;
        a = a > 0.f ? a : NEG * a;
        ushort4 hun = *(const ushort4*)&h[(long long)n * 64 + s * 4];
        float mn = fmaxf(m, a);
        float sc = __expf(m - mn), p = __expf(a - mn);
        l = l * sc + p;
        acc.x = acc.x * sc + p * bf2f(hun.x);
        acc.y = acc.y * sc + p * bf2f(hun.y);
        acc.z = acc.z * sc + p * bf2f(hun.z);
        acc.w = acc.w * sc + p * bf2f(hun.w);
    }
    if (g == 0) {
        float4 o;
        o.x = acc.x / l + bias[s * 4 + 0];
        o.y = acc.y / l + bias[s * 4 + 1];
        o.z = acc.z / l + bias[s * 4 + 2];
        o.w = acc.w / l + bias[s * 4 + 3];
        if (IS_L1) {
            o.x = o.x > 0.f ? o.x : expm1f(o.x);
            o.y = o.y > 0.f ? o.y : expm1f(o.y);
            o.z = o.z > 0.f ? o.z : expm1f(o.z);
            o.w = o.w > 0.f ? o.w : expm1f(o.w);
        }
        *(float4*)&out[(long long)n * 64 + s * 4] = o;
    }
}

__global__ void k_batch(const int* __restrict__ batch, float* __restrict__ out) {
    int t = blockIdx.x * blockDim.x + threadIdx.x;
    if (t >= NN) return;
    out[t] = (float)batch[t];
}

// ============================================================
extern "C" void kernel_launch(void* const* d_in, const int* in_sizes, int n_in,
                              void* d_out, int out_size, void* d_ws, size_t ws_size,
                              hipStream_t stream) {
    const float* x     = (const float*)d_in[0];
    const int*   eidx  = (const int*)d_in[1];
    const float* eattr = (const float*)d_in[2];
    const int*   batch = (const int*)d_in[3];
    const float* W1 = (const float*)d_in[4];
    const float* as1 = (const float*)d_in[5];
    const float* ad1 = (const float*)d_in[6];
    const float* We1 = (const float*)d_in[7];
    const float* vae1 = (const float*)d_in[8];
    const float* b1  = (const float*)d_in[9];
    const float* W2 = (const float*)d_in[10];
    const float* as2 = (const float*)d_in[11];
    const float* ad2 = (const float*)d_in[12];
    const float* We2 = (const float*)d_in[13];
    const float* vae2 = (const float*)d_in[14];
    const float* b2  = (const float*)d_in[15];
    const float* Wm1 = (const float*)d_in[16];
    const float* bm1 = (const float*)d_in[17];
    const float* Wm2 = (const float*)d_in[18];
    const float* bm2 = (const float*)d_in[19];

    const int* src = eidx;
    const int* dst = eidx + NE;

    float* out_h = (float*)d_out;
    float* out_e = out_h + (long long)NN * C;
    float* out_b = out_e + (long long)NE * C;

    // workspace
    uint2* csr    = (uint2*)d_ws;                       // NE (8 B records)
    float* ae1    = (float*)(csr + NE);                 // NE
    float* ae2    = ae1 + NE;                           // NE
    float* out1   = ae2 + NE;                           // NN*64 (fp32, layer-2 input)
    unsigned short* h = (unsigned short*)(out1 + (long long)NN * C); // NN*64 bf16
    float* asrc   = (float*)(h + (long long)NN * C);    // NN
    float* adst   = asrc + NN;                          // NN
    float* vecs   = adst + NN;                          // 512
    int*   hist   = (int*)(vecs + 512);                 // NN
    int*   row_ptr= hist + NN;                          // NN+1
    int*   cursor = row_ptr + NN + 1;                   // NN
    int*   bsum   = cursor + NN;                        // NB

    // hist must be zero before k_mlp_mfma (hist is fused there)
    (void)hipMemsetAsync(hist, 0, sizeof(int) * NN, stream);

    // small vectors
    k_vecs<<<2, 256, 0, stream>>>(We1, vae1, We2, vae2, W1, as1, ad1, W2, as2, ad2, vecs);

    // edge MLP + ae dots + degree hist (single pass over edge_attr)
    k_mlp_mfma<<<NE / 128, 256, 0, stream>>>(eattr, dst, Wm1, bm1, Wm2, bm2, vecs,
                                             out_e, ae1, ae2, hist);

    // CSR build
    k_scan1<<<NB, 256, 0, stream>>>(hist, row_ptr, bsum);
    k_scan2<<<1, 256, 0, stream>>>(bsum);
    k_scan3<<<NB, 256, 0, stream>>>(bsum, row_ptr, cursor);
    k_scatter<<<(NE + 255) / 256, 256, 0, stream>>>(src, dst, ae1, ae2, cursor, csr);

    // GAT layer 1
    k_feat_mfma<IN_DIM><<<(NN + 127) / 128, 256, 0, stream>>>(x, W1, vecs + 128,
                                                              h, asrc, adst, NN);
    k_gat<true><<<(NN + 3) / 4, 256, 0, stream>>>(row_ptr, csr, asrc, adst, h, b1, out1);

    // GAT layer 2
    k_feat_mfma<C><<<(NN + 127) / 128, 256, 0, stream>>>(out1, W2, vecs + 384,
                                                         h, asrc, adst, NN);
    k_gat<false><<<(NN + 3) / 4, 256, 0, stream>>>(row_ptr, csr, asrc, adst, h, b2, out_h);

    // batch passthrough
    k_batch<<<(NN + 255) / 256, 256, 0, stream>>>(batch, out_b);
}